// Round 1
// baseline (233.815 us; speedup 1.0000x reference)
//
#include <hip/hip_runtime.h>

// Forward-fill imputation (SIMPLE.imputate):
//   observed = mask < 0.9
//   gather_idx[b,n] = index of most recent observed pos <= n,
//                     wrap-around: leading missing use row's LAST observed idx,
//                     guard: row with no observed -> 0
//   out[b,n,:] = in[b, gather_idx[b,n], :]
//
// B=64, N=4096, D=128, fp32. Memory-bound: ~134MB write + ~121MB read.

#define FF_N 4096
#define FF_D 128

// ---------- Phase 1: per-row inclusive max-scan of observed indices ----------
// One block (256 threads) per batch row. Each thread owns 16 contiguous
// elements; segment max -> 256-wide Hillis-Steele max-scan in LDS -> serial
// forward fill within segment. Writes gather_idx (int32) to workspace.
__global__ __launch_bounds__(256) void ffill_scan(const float* __restrict__ mask,
                                                  int* __restrict__ gidx) {
    const int N = FF_N;
    const int PER = 16;               // N / 256
    const int b = blockIdx.x;
    const float* m = mask + (size_t)b * N;
    int* g = gidx + (size_t)b * N;
    const int tid = threadIdx.x;
    const int base = tid * PER;

    // Vectorized mask load: 4 x float4 = 16 floats (64B per thread, aligned).
    float4 mv[4];
    const float4* m4 = reinterpret_cast<const float4*>(m + base);
#pragma unroll
    for (int k = 0; k < 4; ++k) mv[k] = m4[k];

    unsigned obsbits = 0;
    int segmax = -1;
#pragma unroll
    for (int k = 0; k < 4; ++k) {
        const float vals[4] = {mv[k].x, mv[k].y, mv[k].z, mv[k].w};
#pragma unroll
        for (int j = 0; j < 4; ++j) {
            const int idx = k * 4 + j;
            const bool o = vals[j] < 0.9f;   // observed
            obsbits |= (unsigned)o << idx;
            if (o) segmax = base + idx;
        }
    }

    // Block-wide inclusive max-scan of segment maxima (Hillis-Steele, LDS).
    __shared__ int smem[256];
    smem[tid] = segmax;
    __syncthreads();
    int v = segmax;
#pragma unroll
    for (int off = 1; off < 256; off <<= 1) {
        const int t = (tid >= off) ? smem[tid - off] : -1;
        __syncthreads();
        v = max(v, t);
        smem[tid] = v;
        __syncthreads();
    }
    const int prefix = tid ? smem[tid - 1] : -1;  // exclusive prefix for my segment
    const int total  = smem[255];                 // row's last observed idx overall
    const int fallback = (total < 0) ? 0 : total; // guard: no observed in row

    // Serial forward fill within my 16 elements.
    int outv[16];
    int last = prefix;
#pragma unroll
    for (int k = 0; k < PER; ++k) {
        if ((obsbits >> k) & 1u) last = base + k;
        outv[k] = (last < 0) ? fallback : last;
    }

    int4* g4 = reinterpret_cast<int4*>(g + base);
#pragma unroll
    for (int k = 0; k < 4; ++k)
        g4[k] = make_int4(outv[4 * k], outv[4 * k + 1], outv[4 * k + 2], outv[4 * k + 3]);
}

// ---------- Phase 2: gather rows of D=128 floats as float4 ----------
// q indexes float4 elements of the output. 32 float4 per (b,n) row; 32
// consecutive lanes read one contiguous 512B source row (coalesced), writes
// fully contiguous. gidx load is a 32-lane broadcast (L1 hit).
__global__ __launch_bounds__(256) void ffill_gather(const float4* __restrict__ in,
                                                    const int* __restrict__ gidx,
                                                    float4* __restrict__ out,
                                                    int total4) {
    const int stride = gridDim.x * blockDim.x;
    for (int q = blockIdx.x * blockDim.x + threadIdx.x; q < total4; q += stride) {
        const int row = q >> 5;                    // b*N + n   (32 float4 per row)
        const int l   = q & 31;
        const int gi  = gidx[row];
        const int srow = (row & ~(FF_N - 1)) + gi; // b*N + gather_idx
        out[q] = in[(size_t)srow * (FF_D / 4) + l];
    }
}

extern "C" void kernel_launch(void* const* d_in, const int* in_sizes, int n_in,
                              void* d_out, int out_size, void* d_ws, size_t ws_size,
                              hipStream_t stream) {
    const float* inp  = (const float*)d_in[0];   // [B, N, D] fp32
    const float* mask = (const float*)d_in[1];   // [B, N]    fp32
    float* out = (float*)d_out;

    const int B = in_sizes[1] / FF_N;            // 64
    int* gidx = (int*)d_ws;                      // B*N*4 = 1 MiB scratch

    ffill_scan<<<B, 256, 0, stream>>>(mask, gidx);

    const int total4 = B * FF_N * (FF_D / 4);    // 8,388,608 float4
    ffill_gather<<<2048, 256, 0, stream>>>(
        (const float4*)inp, gidx, (float4*)out, total4);
}